// Round 4
// baseline (281.553 us; speedup 1.0000x reference)
//
#include <hip/hip_runtime.h>
#include <hip/hip_fp16.h>
#include <math.h>

#define NATOM 8192  // NB * NLOC

namespace {

typedef _Float16 half8 __attribute__((ext_vector_type(8)));
typedef _Float16 half2t __attribute__((ext_vector_type(2)));
typedef float f32x4 __attribute__((ext_vector_type(4)));

constexpr int VB_STRIDE = 260;   // vbuf row stride in halfs (256 + 4 pad)

// ws layout (halfs): [0,32768) wkvp | [32768,49152) Wqp_t | [49152,65536) Whp_t
__global__ void pack_weights(const float* __restrict__ Wkv,
                             const float* __restrict__ Wq,
                             const float* __restrict__ Wh,
                             _Float16* __restrict__ out) {
  int tid = blockIdx.x * 256 + threadIdx.x;  // 0..65535
  if (tid < 32768) {
    // A-fragment order for mfma_f32_16x16x32_f16 computing C^T = Wkv^T @ gg1^T
    int jj = tid & 7;
    int l  = (tid >> 3) & 63;
    int ks = (tid >> 9) & 1;
    int ct = tid >> 10;
    int i  = ks * 32 + ((l >> 4) << 3) + jj;
    int c  = ct * 16 + (l & 15);
    out[tid] = (_Float16)Wkv[i * 512 + c];
  } else if (tid < 49152) {
    int idx = tid - 32768;          // Wqp_t[c][i] = Wq[i][c]
    int c = idx >> 6, i = idx & 63;
    out[tid] = (_Float16)Wq[i * 256 + c];
  } else {
    int idx = tid - 49152;          // Whp_t[c][k] = Wh[k][c]
    int c = idx >> 8, k = idx & 255;
    out[tid] = (_Float16)Wh[k * 64 + c];
  }
}

__device__ __forceinline__ float dot8(half8 a, half8 b, float acc) {
  acc = __builtin_amdgcn_fdot2((half2t){a[0], a[1]}, (half2t){b[0], b[1]}, acc, false);
  acc = __builtin_amdgcn_fdot2((half2t){a[2], a[3]}, (half2t){b[2], b[3]}, acc, false);
  acc = __builtin_amdgcn_fdot2((half2t){a[4], a[5]}, (half2t){b[4], b[5]}, acc, false);
  acc = __builtin_amdgcn_fdot2((half2t){a[6], a[7]}, (half2t){b[6], b[7]}, acc, false);
  return acc;
}

__global__ __launch_bounds__(256, 4)
void local_atten_kernel(const float* __restrict__ g1,
                        const float* __restrict__ gg1,
                        const int* __restrict__ mask,
                        const _Float16* __restrict__ wpack,
                        const float* __restrict__ bh,
                        float* __restrict__ out) {
  // LDS: 33280 + 128 + 3072 + 512 + 512 = 37504 B -> 4 blocks/CU
  __shared__ __align__(16) __half vraw[64 * VB_STRIDE]; // vbuf; first 8 KB aliased as gs
  __shared__ __align__(16) __half g1h[64];
  __shared__ __align__(16) unsigned char blob[3072];    // qs(1024)+sred(2048) / redbuf2(2048)+redbuf(1024)
  __shared__ __align__(8) __half aws2[64][4];           // softmax weights [j][h]
  __shared__ __align__(16) __half rets[256];            // o flat k = h*64 + d

  float* qs = reinterpret_cast<float*>(blob);                    // [256] fp32
  __half (*sred)[4][64] = reinterpret_cast<__half(*)[4][64]>(blob + 1024);  // [w][h][j]
  __half (*redbuf2)[64][4] = reinterpret_cast<__half(*)[64][4]>(blob);      // [jq][d][h]
  float (*redbuf)[64] = reinterpret_cast<float(*)[64]>(blob + 2048);        // [w][c]

  const _Float16* wkvp = wpack;
  const _Float16* wqp  = wpack + 32768;
  const _Float16* whp  = wpack + 49152;

  const int t = threadIdx.x;
  const int lane = t & 63;
  const int wave = t >> 6;
  const int lq = lane >> 4;   // quad within wave
  const int lr = lane & 15;
  const int atom = blockIdx.x;

  __half* gs = vraw;                                      // alias (staging phase only)
  auto vbuf = reinterpret_cast<__half(*)[VB_STRIDE]>(vraw);

  if (t < 64) g1h[t] = __float2half(g1[(size_t)atom * 64 + t]);

  // ---- stage gg1 tile (64 nei x 64 feat) as fp16, swizzled for B-frag b128 ----
  // logical gs[j][i]; physical half offset = j*64 + ((g ^ (j&7))<<3) + (i&7), g=i>>3
  {
    const float4* src = reinterpret_cast<const float4*>(gg1 + (size_t)atom * 4096);
#pragma unroll
    for (int r = 0; r < 4; ++r) {
      int idx4 = t + 256 * r;          // 0..1023 float4s
      int j = idx4 >> 4;               // neighbor row
      int i4 = (idx4 & 15) << 2;       // feature start (multiple of 4)
      float4 v = src[idx4];
      __half2 h01 = __floats2half2_rn(v.x, v.y);
      __half2 h23 = __floats2half2_rn(v.z, v.w);
      int g = i4 >> 3;
      int addr = j * 64 + ((g ^ (j & 7)) << 3) + (i4 & 7);
      union { __half2 h[2]; uint2 u; } pk;
      pk.h[0] = h01; pk.h[1] = h23;
      *reinterpret_cast<uint2*>(&gs[addr]) = pk.u;
    }
  }
  __syncthreads();

  // ---- B-fragments (gg1) for all 4 j-tiles x 2 k-steps, kept in regs ----
  half8 bfrag[4][2];
#pragma unroll
  for (int jt = 0; jt < 4; ++jt) {
#pragma unroll
    for (int ks = 0; ks < 2; ++ks) {
      int j = jt * 16 + lr;
      int g = ks * 4 + lq;
      bfrag[jt][ks] =
          *reinterpret_cast<const half8*>(&gs[j * 64 + ((g ^ (j & 7)) << 3)]);
    }
  }

  // ---- q = g1row @ Wq (fp16 dot2): thread t owns flat column t (= d*4 + h) ----
  {
    float qacc = 0.f;
    const half8* wrow = reinterpret_cast<const half8*>(wqp + t * 64);
    const half8* grow = reinterpret_cast<const half8*>(&g1h[0]);
#pragma unroll
    for (int ks = 0; ks < 8; ++ks) qacc = dot8(wrow[ks], grow[ks], qacc);
    qs[t] = qacc;
  }
  __syncthreads();   // bfrags read (gs dead), qs ready -> vbuf may overwrite gs

  // ---- kv GEMM via MFMA; k consumed into register score partials, v -> LDS ----
  // Lane holds C'[c = ct*16 + lq*4 + r][j = jt*16 + lr]; even quads: k (head=r),
  // odd quads: v (head=r); d = ct*2 + (lq>>1).
  float sacc[4][4];  // [jt][h], meaningful on even-quad lanes
#pragma unroll
  for (int jt = 0; jt < 4; ++jt)
#pragma unroll
    for (int h = 0; h < 4; ++h) sacc[jt][h] = 0.f;

  const bool isv = (lq & 1);
#pragma unroll 2
  for (int it = 0; it < 8; ++it) {
    const int ct = ((it >> 2) << 4) + wave * 4 + (it & 3);  // 16-col tile (0..31)
    const half8* ap = reinterpret_cast<const half8*>(wkvp) + ct * 128;
    half8 a0 = ap[lane];        // ks=0
    half8 a1 = ap[64 + lane];   // ks=1
    const int d = ct * 2 + (lq >> 1);

    f32x4 accs[4];
#pragma unroll
    for (int jt = 0; jt < 4; ++jt) {
      f32x4 acc = {0.f, 0.f, 0.f, 0.f};
      acc = __builtin_amdgcn_mfma_f32_16x16x32_f16(a0, bfrag[jt][0], acc, 0, 0, 0);
      acc = __builtin_amdgcn_mfma_f32_16x16x32_f16(a1, bfrag[jt][1], acc, 0, 0, 0);
      accs[jt] = acc;
    }

    if (isv) {
#pragma unroll
      for (int jt = 0; jt < 4; ++jt) {
        int j = jt * 16 + lr;
        __half2 h01 = __floats2half2_rn(accs[jt][0], accs[jt][1]);
        __half2 h23 = __floats2half2_rn(accs[jt][2], accs[jt][3]);
        union { __half2 h[2]; uint2 u; } pk;
        pk.h[0] = h01; pk.h[1] = h23;
        *reinterpret_cast<uint2*>(&vbuf[j][d * 4]) = pk.u;
      }
    } else {
      float4 q4 = *reinterpret_cast<const float4*>(&qs[d * 4]);  // broadcast b128
#pragma unroll
      for (int jt = 0; jt < 4; ++jt) {
        sacc[jt][0] = fmaf(accs[jt][0], q4.x, sacc[jt][0]);
        sacc[jt][1] = fmaf(accs[jt][1], q4.y, sacc[jt][1]);
        sacc[jt][2] = fmaf(accs[jt][2], q4.z, sacc[jt][2]);
        sacc[jt][3] = fmaf(accs[jt][3], q4.w, sacc[jt][3]);
      }
    }
  }

  // fold even quads (lq=0 <- lq=2, lane XOR 32) and publish score partials
#pragma unroll
  for (int jt = 0; jt < 4; ++jt)
#pragma unroll
    for (int h = 0; h < 4; ++h)
      sacc[jt][h] += __shfl_xor(sacc[jt][h], 32);
  if (lq == 0) {
#pragma unroll
    for (int h = 0; h < 4; ++h)
#pragma unroll
      for (int jt = 0; jt < 4; ++jt)
        sred[wave][h][jt * 16 + lr] = __float2half(sacc[jt][h]);
  }
  __syncthreads();

  // ---- masked softmax over j (wave-wide): h = wave, j = lane ----
  {
    float s = __half2float(sred[0][wave][lane]) + __half2float(sred[1][wave][lane]) +
              __half2float(sred[2][wave][lane]) + __half2float(sred[3][wave][lane]);
    s *= 0.125f;                                          // 1/sqrt(64)
    const int m = mask[(size_t)atom * 64 + lane];
    s = m ? s : -INFINITY;
    float mx = s;
#pragma unroll
    for (int off = 32; off > 0; off >>= 1) mx = fmaxf(mx, __shfl_xor(mx, off));
    float pe = m ? __expf(s - mx) : 0.f;
    float sum = pe;
#pragma unroll
    for (int off = 32; off > 0; off >>= 1) sum += __shfl_xor(sum, off);
    float aw = (sum > 0.f) ? (pe / sum) : 0.f;
    aws2[lane][wave] = __float2half(aw);                  // [j][h]
  }
  __syncthreads();   // also: sred/qs dead; blob may be reused as redbuf2

  // ---- PV: thread (d=lane, jq=wave) accumulates o_part[h] over its j-quarter ----
  {
    __half2 o01 = __float2half2_rn(0.f), o23 = __float2half2_rn(0.f);
#pragma unroll
    for (int jj = 0; jj < 16; ++jj) {
      int j = wave * 16 + jj;
      union { uint2 u; __half2 h[2]; } aw, vv;
      aw.u = *reinterpret_cast<const uint2*>(&aws2[j][0]);          // broadcast b64
      vv.u = *reinterpret_cast<const uint2*>(&vbuf[j][lane * 4]);   // conflict-free b64
      o01 = __hfma2(aw.h[0], vv.h[0], o01);
      o23 = __hfma2(aw.h[1], vv.h[1], o23);
    }
    union { uint2 u; __half2 h[2]; } pk;
    pk.h[0] = o01; pk.h[1] = o23;
    *reinterpret_cast<uint2*>(&redbuf2[wave][lane][0]) = pk.u;
  }
  __syncthreads();

  // ---- ret[h*64+d] = sum_jq o_part : thread (h=wave, d=lane) ----
  {
    float r = 0.f;
#pragma unroll
    for (int jq = 0; jq < 4; ++jq) r += __half2float(redbuf2[jq][lane][wave]);
    rets[wave * 64 + lane] = __float2half(r);
  }
  __syncthreads();

  // ---- out = ret @ Wh + bh (fp16 dot2): c = lane, k-range = wave*64.. ----
  {
    float part = 0.f;
    const half8* wrow = reinterpret_cast<const half8*>(whp + lane * 256 + wave * 64);
    const half8* rrow = reinterpret_cast<const half8*>(&rets[wave * 64]);  // broadcast
#pragma unroll
    for (int ks = 0; ks < 8; ++ks) part = dot8(wrow[ks], rrow[ks], part);
    redbuf[wave][lane] = part;
  }
  __syncthreads();
  if (t < 64)
    out[(size_t)atom * 64 + t] =
        redbuf[0][t] + redbuf[1][t] + redbuf[2][t] + redbuf[3][t] + bh[t];
}

}  // namespace

extern "C" void kernel_launch(void* const* d_in, const int* in_sizes, int n_in,
                              void* d_out, int out_size, void* d_ws, size_t ws_size,
                              hipStream_t stream) {
  const float* g1   = (const float*)d_in[0];
  const float* gg1  = (const float*)d_in[1];
  const int*   mask = (const int*)d_in[2];
  const float* Wq   = (const float*)d_in[3];
  const float* Wkv  = (const float*)d_in[4];
  const float* Wh   = (const float*)d_in[5];
  const float* bh   = (const float*)d_in[6];
  float* out = (float*)d_out;
  (void)in_sizes; (void)n_in; (void)ws_size; (void)out_size;

  _Float16* wpack = (_Float16*)d_ws;   // 65536 halfs = 128 KB
  pack_weights<<<256, 256, 0, stream>>>(Wkv, Wq, Wh, wpack);
  local_atten_kernel<<<NATOM, 256, 0, stream>>>(g1, gg1, mask, wpack, bh, out);
}

// Round 5
// 269.484 us; speedup vs baseline: 1.0448x; 1.0448x over previous
//
#include <hip/hip_runtime.h>
#include <hip/hip_fp16.h>
#include <math.h>

#define NATOM 8192  // NB * NLOC

namespace {

typedef _Float16 half8 __attribute__((ext_vector_type(8)));
typedef _Float16 half2t __attribute__((ext_vector_type(2)));
typedef float f32x4 __attribute__((ext_vector_type(4)));

constexpr int VB_STRIDE = 260;   // vbuf row stride in halfs (256 + 4 pad)

// ws layout (halfs): [0,32768) wkvp | [32768,49152) Wqp_t | [49152,65536) Whp_t
// Coalesced READS, scattered writes (posted, latency-free).
__global__ void pack_weights(const float* __restrict__ Wkv,
                             const float* __restrict__ Wq,
                             const float* __restrict__ Wh,
                             _Float16* __restrict__ out) {
  int tid = blockIdx.x * 256 + threadIdx.x;  // 0..65535
  if (tid < 32768) {
    // (i,c) with c fastest -> coalesced read of Wkv[i][c]
    int i = tid >> 9, c = tid & 511;
    int ks = i >> 5, jj = i & 7, lq = (i >> 3) & 3;
    int ct = c >> 4, lr = c & 15;
    int l = lq * 16 + lr;
    out[(((ct * 2 + ks) * 64) + l) * 8 + jj] = (_Float16)Wkv[i * 512 + c];
  } else if (tid < 49152) {
    int idx = tid - 32768;          // Wq is [i][c], 64x256
    int i = idx >> 8, c = idx & 255;
    out[32768 + c * 64 + i] = (_Float16)Wq[i * 256 + c];   // Wqp_t[c][i]
  } else {
    int idx = tid - 49152;          // Wh is [k][c], 256x64
    int k = idx >> 6, c = idx & 63;
    out[49152 + c * 256 + k] = (_Float16)Wh[k * 64 + c];   // Whp_t[c][k]
  }
}

__device__ __forceinline__ float dot8(half8 a, half8 b, float acc) {
  acc = __builtin_amdgcn_fdot2((half2t){a[0], a[1]}, (half2t){b[0], b[1]}, acc, false);
  acc = __builtin_amdgcn_fdot2((half2t){a[2], a[3]}, (half2t){b[2], b[3]}, acc, false);
  acc = __builtin_amdgcn_fdot2((half2t){a[4], a[5]}, (half2t){b[4], b[5]}, acc, false);
  acc = __builtin_amdgcn_fdot2((half2t){a[6], a[7]}, (half2t){b[6], b[7]}, acc, false);
  return acc;
}

__global__ __launch_bounds__(256, 4)
void local_atten_kernel(const float* __restrict__ g1,
                        const float* __restrict__ gg1,
                        const int* __restrict__ mask,
                        const _Float16* __restrict__ wpack,
                        const float* __restrict__ bh,
                        float* __restrict__ out) {
  // LDS: 33280 + 128 + 3072 + 512 + 512 = 37504 B -> 4 blocks/CU
  __shared__ __align__(16) __half vraw[64 * VB_STRIDE]; // vbuf; first 8 KB aliased as gs
  __shared__ __align__(16) __half g1h[64];
  __shared__ __align__(16) unsigned char blob[3072];    // qs+sred / redbuf2+redbuf
  __shared__ __align__(8) __half aws2[64][4];           // softmax weights [j][h]
  __shared__ __align__(16) __half rets[256];            // o flat k = h*64 + d

  float* qs = reinterpret_cast<float*>(blob);                    // [256] fp32
  __half (*sred)[4][64] = reinterpret_cast<__half(*)[4][64]>(blob + 1024);  // [w][h][j]
  __half (*redbuf2)[64][4] = reinterpret_cast<__half(*)[64][4]>(blob);      // [jq][d][h]
  float (*redbuf)[64] = reinterpret_cast<float(*)[64]>(blob + 2048);        // [w][c]

  const _Float16* wkvp = wpack;
  const _Float16* wqp  = wpack + 32768;
  const _Float16* whp  = wpack + 49152;

  const int t = threadIdx.x;
  const int lane = t & 63;
  const int wave = t >> 6;
  const int lq = lane >> 4;   // quad within wave
  const int lr = lane & 15;
  const int atom = blockIdx.x;

  __half* gs = vraw;                                      // alias (staging phase only)
  auto vbuf = reinterpret_cast<__half(*)[VB_STRIDE]>(vraw);

  // ---- hoisted small loads: latency hidden behind staging + first barrier ----
  const int mreg = mask[(size_t)atom * 64 + lane];
  const float bhv = bh[lane];
  if (t < 64) g1h[t] = __float2half(g1[(size_t)atom * 64 + t]);

  // ---- stage gg1 tile (64 nei x 64 feat) as fp16, swizzled for B-frag b128 ----
  // logical gs[j][i]; physical half offset = j*64 + ((g ^ (j&7))<<3) + (i&7), g=i>>3
  {
    const float4* src = reinterpret_cast<const float4*>(gg1 + (size_t)atom * 4096);
#pragma unroll
    for (int r = 0; r < 4; ++r) {
      int idx4 = t + 256 * r;          // 0..1023 float4s
      int j = idx4 >> 4;               // neighbor row
      int i4 = (idx4 & 15) << 2;       // feature start (multiple of 4)
      float4 v = src[idx4];
      __half2 h01 = __floats2half2_rn(v.x, v.y);
      __half2 h23 = __floats2half2_rn(v.z, v.w);
      int g = i4 >> 3;
      int addr = j * 64 + ((g ^ (j & 7)) << 3) + (i4 & 7);
      union { __half2 h[2]; uint2 u; } pk;
      pk.h[0] = h01; pk.h[1] = h23;
      *reinterpret_cast<uint2*>(&gs[addr]) = pk.u;
    }
  }
  __syncthreads();

  // ---- B-fragments (gg1) for all 4 j-tiles x 2 k-steps, kept in regs ----
  half8 bfrag[4][2];
#pragma unroll
  for (int jt = 0; jt < 4; ++jt) {
#pragma unroll
    for (int ks = 0; ks < 2; ++ks) {
      int j = jt * 16 + lr;
      int g = ks * 4 + lq;
      bfrag[jt][ks] =
          *reinterpret_cast<const half8*>(&gs[j * 64 + ((g ^ (j & 7)) << 3)]);
    }
  }

  // ---- prefetch first A-fragments (consumed after the barrier) ----
  const half8* ap_base = reinterpret_cast<const half8*>(wkvp);
  half8 a0 = ap_base[(wave * 4) * 128 + lane];
  half8 a1 = ap_base[(wave * 4) * 128 + 64 + lane];

  // ---- q = g1row @ Wq (fp16 dot2): thread t owns flat column t (= d*4 + h) ----
  {
    float qacc = 0.f;
    const half8* wrow = reinterpret_cast<const half8*>(wqp + t * 64);
    const half8* grow = reinterpret_cast<const half8*>(&g1h[0]);
#pragma unroll
    for (int ks = 0; ks < 8; ++ks) qacc = dot8(wrow[ks], grow[ks], qacc);
    qs[t] = qacc;
  }
  __syncthreads();   // bfrags read (gs dead), qs ready -> vbuf may overwrite gs

  // ---- kv GEMM via MFMA; k consumed into register score partials, v -> LDS ----
  // Lane holds C'[c = ct*16 + lq*4 + r][j = jt*16 + lr]; even quads: k (head=r),
  // odd quads: v (head=r); d = ct*2 + (lq>>1).
  float sacc[4][4];  // [jt][h], meaningful on even-quad lanes
#pragma unroll
  for (int jt = 0; jt < 4; ++jt)
#pragma unroll
    for (int h = 0; h < 4; ++h) sacc[jt][h] = 0.f;

  const bool isv = (lq & 1);
#pragma unroll
  for (int it = 0; it < 8; ++it) {
    const int ct = ((it >> 2) << 4) + wave * 4 + (it & 3);  // 16-col tile (0..31)
    const int d = ct * 2 + (lq >> 1);

    // prefetch next iteration's A-fragments (depth-1 software pipeline)
    half8 na0 = a0, na1 = a1;
    if (it < 7) {
      const int nit = it + 1;
      const int nct = ((nit >> 2) << 4) + wave * 4 + (nit & 3);
      na0 = ap_base[nct * 128 + lane];
      na1 = ap_base[nct * 128 + 64 + lane];
    }

    f32x4 accs[4];
#pragma unroll
    for (int jt = 0; jt < 4; ++jt) {
      f32x4 acc = {0.f, 0.f, 0.f, 0.f};
      acc = __builtin_amdgcn_mfma_f32_16x16x32_f16(a0, bfrag[jt][0], acc, 0, 0, 0);
      acc = __builtin_amdgcn_mfma_f32_16x16x32_f16(a1, bfrag[jt][1], acc, 0, 0, 0);
      accs[jt] = acc;
    }

    if (isv) {
#pragma unroll
      for (int jt = 0; jt < 4; ++jt) {
        int j = jt * 16 + lr;
        __half2 h01 = __floats2half2_rn(accs[jt][0], accs[jt][1]);
        __half2 h23 = __floats2half2_rn(accs[jt][2], accs[jt][3]);
        union { __half2 h[2]; uint2 u; } pk;
        pk.h[0] = h01; pk.h[1] = h23;
        *reinterpret_cast<uint2*>(&vbuf[j][d * 4]) = pk.u;
      }
    } else {
      float4 q4 = *reinterpret_cast<const float4*>(&qs[d * 4]);  // broadcast b128
#pragma unroll
      for (int jt = 0; jt < 4; ++jt) {
        sacc[jt][0] = fmaf(accs[jt][0], q4.x, sacc[jt][0]);
        sacc[jt][1] = fmaf(accs[jt][1], q4.y, sacc[jt][1]);
        sacc[jt][2] = fmaf(accs[jt][2], q4.z, sacc[jt][2]);
        sacc[jt][3] = fmaf(accs[jt][3], q4.w, sacc[jt][3]);
      }
    }
    a0 = na0; a1 = na1;
  }

  // fold even quads (lq=0 <- lq=2, lane XOR 32) and publish score partials
#pragma unroll
  for (int jt = 0; jt < 4; ++jt)
#pragma unroll
    for (int h = 0; h < 4; ++h)
      sacc[jt][h] += __shfl_xor(sacc[jt][h], 32);
  if (lq == 0) {
#pragma unroll
    for (int h = 0; h < 4; ++h)
#pragma unroll
      for (int jt = 0; jt < 4; ++jt)
        sred[wave][h][jt * 16 + lr] = __float2half(sacc[jt][h]);
  }
  __syncthreads();

  // ---- preload epilogue Wh fragments (regs free here; hides L2 latency) ----
  half8 wh_frag[8];
  {
    const half8* wrow = reinterpret_cast<const half8*>(whp + lane * 256 + wave * 64);
#pragma unroll
    for (int ks = 0; ks < 8; ++ks) wh_frag[ks] = wrow[ks];
  }

  // ---- masked softmax over j (wave-wide): h = wave, j = lane ----
  {
    float s = __half2float(sred[0][wave][lane]) + __half2float(sred[1][wave][lane]) +
              __half2float(sred[2][wave][lane]) + __half2float(sred[3][wave][lane]);
    s *= 0.125f;                                          // 1/sqrt(64)
    s = mreg ? s : -INFINITY;
    float mx = s;
#pragma unroll
    for (int off = 32; off > 0; off >>= 1) mx = fmaxf(mx, __shfl_xor(mx, off));
    float pe = mreg ? __expf(s - mx) : 0.f;
    float sum = pe;
#pragma unroll
    for (int off = 32; off > 0; off >>= 1) sum += __shfl_xor(sum, off);
    float aw = (sum > 0.f) ? (pe / sum) : 0.f;
    aws2[lane][wave] = __float2half(aw);                  // [j][h]
  }
  __syncthreads();   // also: sred/qs dead; blob may be reused as redbuf2

  // ---- PV: thread (d=lane, jq=wave) accumulates o_part[h] over its j-quarter ----
  {
    __half2 o01 = __float2half2_rn(0.f), o23 = __float2half2_rn(0.f);
#pragma unroll
    for (int jj = 0; jj < 16; ++jj) {
      int j = wave * 16 + jj;
      union { uint2 u; __half2 h[2]; } aw, vv;
      aw.u = *reinterpret_cast<const uint2*>(&aws2[j][0]);          // broadcast b64
      vv.u = *reinterpret_cast<const uint2*>(&vbuf[j][lane * 4]);   // conflict-free b64
      o01 = __hfma2(aw.h[0], vv.h[0], o01);
      o23 = __hfma2(aw.h[1], vv.h[1], o23);
    }
    union { uint2 u; __half2 h[2]; } pk;
    pk.h[0] = o01; pk.h[1] = o23;
    *reinterpret_cast<uint2*>(&redbuf2[wave][lane][0]) = pk.u;
  }
  __syncthreads();

  // ---- ret[h*64+d] = sum_jq o_part : thread (h=wave, d=lane) ----
  {
    float r = 0.f;
#pragma unroll
    for (int jq = 0; jq < 4; ++jq) r += __half2float(redbuf2[jq][lane][wave]);
    rets[wave * 64 + lane] = __float2half(r);
  }
  // NO barrier: epilogue reads only rets[wave*64 + *], written by this same wave
  // (wave-internal LDS RAW is ordered by lgkmcnt, which the compiler inserts).

  // ---- out = ret @ Wh + bh (fp16 dot2): c = lane, k-range = wave*64.. ----
  {
    float part = 0.f;
    const half8* rrow = reinterpret_cast<const half8*>(&rets[wave * 64]);  // broadcast
#pragma unroll
    for (int ks = 0; ks < 8; ++ks) part = dot8(wh_frag[ks], rrow[ks], part);
    redbuf[wave][lane] = part;
  }
  __syncthreads();
  if (t < 64)
    out[(size_t)atom * 64 + t] =
        redbuf[0][t] + redbuf[1][t] + redbuf[2][t] + redbuf[3][t] + bhv;
}

}  // namespace

extern "C" void kernel_launch(void* const* d_in, const int* in_sizes, int n_in,
                              void* d_out, int out_size, void* d_ws, size_t ws_size,
                              hipStream_t stream) {
  const float* g1   = (const float*)d_in[0];
  const float* gg1  = (const float*)d_in[1];
  const int*   mask = (const int*)d_in[2];
  const float* Wq   = (const float*)d_in[3];
  const float* Wkv  = (const float*)d_in[4];
  const float* Wh   = (const float*)d_in[5];
  const float* bh   = (const float*)d_in[6];
  float* out = (float*)d_out;
  (void)in_sizes; (void)n_in; (void)ws_size; (void)out_size;

  _Float16* wpack = (_Float16*)d_ws;   // 65536 halfs = 128 KB
  pack_weights<<<256, 256, 0, stream>>>(Wkv, Wq, Wh, wpack);
  local_atten_kernel<<<NATOM, 256, 0, stream>>>(g1, gg1, mask, wpack, bh, out);
}